// Round 1
// baseline (1235.714 us; speedup 1.0000x reference)
//
#include <hip/hip_runtime.h>
#include <cstdint>

// GridEncoder forward (torch-ngp semantics), MI355X.
// B = 1048576 points, D=3, L=16 levels, C=2, H=16, per_level_scale=2.0,
// log2_hashmap_size=19, align_corners=False.
//
// Level metadata (computed from the reference's _level_meta()):
//   res(l)   = 16 << l
//   scale(l) = res - 1            (exact in fp32: exp2(l)*16 - 1)
//   dense levels: 0,1,2 (offsets 0, 4920, 40864), base = res+1,
//     idx = cx + cy*base + cz*base^2   (mod size is identity: idx < full <= size)
//   hashed levels: 3..15, size = 2^19 -> idx = hash & 0x7FFFF
//     offset(l) = 315496 + (l-3)*524288 = l*524288 - 1257368
//   fast_hash primes: (1, 2654435761, 805459861)
//
// Thread layout: t = global thread id, p = t>>4, l = t&15.
// out is float2[B*16]; out[p*16+l] == out[t] -> stores are perfectly coalesced.

namespace {

__global__ __launch_bounds__(256) void grid_encode_kernel(
    const float* __restrict__ in,      // [B,3] in [-1,1]
    const float2* __restrict__ emb,    // [7131240] float2
    float2* __restrict__ out,          // [B*16] float2
    uint32_t B) {
  uint32_t t = blockIdx.x * 256u + threadIdx.x;
  uint32_t p = t >> 4;
  uint32_t l = t & 15u;
  if (p >= B) return;

  // map [-1,1] -> [0,1]
  float x = (in[p * 3 + 0] + 1.0f) * 0.5f;
  float y = (in[p * 3 + 1] + 1.0f) * 0.5f;
  float z = (in[p * 3 + 2] + 1.0f) * 0.5f;

  uint32_t res = 16u << l;
  float scale = (float)res - 1.0f;

  float px = x * scale + 0.5f;
  float py = y * scale + 0.5f;
  float pz = z * scale + 0.5f;
  float gx = floorf(px), gy = floorf(py), gz = floorf(pz);
  float rx = px - gx, ry = py - gy, rz = pz - gz;
  uint32_t ix = (uint32_t)gx, iy = (uint32_t)gy, iz = (uint32_t)gz;

  // per-level offset into the embedding table (closed form)
  uint32_t off = (l >= 3u) ? (l * 524288u - 1257368u)
                           : ((l == 0u) ? 0u : ((l == 1u) ? 4920u : 40864u));
  bool hashed = (l >= 3u);

  uint32_t base = res + 1u;
  uint32_t bb = base * base;
  const uint32_t P2 = 2654435761u, P3 = 805459861u;

  // precompute the two possible y/z contributions for dense and hash paths
  uint32_t dy0 = iy * base, dy1 = dy0 + base;
  uint32_t dz0 = iz * bb,   dz1 = dz0 + bb;
  uint32_t hy0 = iy * P2,   hy1 = hy0 + P2;
  uint32_t hz0 = iz * P3,   hz1 = hz0 + P3;

  // all 8 corner indices up front (maximize memory-level parallelism)
  uint32_t idx[8];
#pragma unroll
  for (int c = 0; c < 8; ++c) {
    uint32_t bx = (uint32_t)(c & 1), by = (uint32_t)((c >> 1) & 1),
             bz = (uint32_t)((c >> 2) & 1);
    uint32_t cx = ix + bx;
    uint32_t h = (cx ^ (by ? hy1 : hy0) ^ (bz ? hz1 : hz0)) & 0x7FFFFu;
    uint32_t d = cx + (by ? dy1 : dy0) + (bz ? dz1 : dz0);
    idx[c] = (hashed ? h : d) + off;
  }

  float2 e[8];
#pragma unroll
  for (int c = 0; c < 8; ++c) e[c] = emb[idx[c]];

  float wx1 = rx, wx0 = 1.0f - rx;
  float wy1 = ry, wy0 = 1.0f - ry;
  float wz1 = rz, wz0 = 1.0f - rz;
  float o0 = 0.0f, o1 = 0.0f;
#pragma unroll
  for (int c = 0; c < 8; ++c) {
    float w = ((c & 1) ? wx1 : wx0) *
              ((c & 2) ? wy1 : wy0) *
              ((c & 4) ? wz1 : wz0);
    o0 = fmaf(w, e[c].x, o0);
    o1 = fmaf(w, e[c].y, o1);
  }

  out[t] = make_float2(o0, o1);
}

}  // namespace

extern "C" void kernel_launch(void* const* d_in, const int* in_sizes, int n_in,
                              void* d_out, int out_size, void* d_ws, size_t ws_size,
                              hipStream_t stream) {
  (void)n_in; (void)out_size; (void)d_ws; (void)ws_size;
  const float* in = (const float*)d_in[0];
  const float2* emb = (const float2*)d_in[1];
  float2* out = (float2*)d_out;
  uint32_t B = (uint32_t)(in_sizes[0] / 3);
  uint32_t total = B * 16u;            // one thread per (point, level)
  uint32_t blocks = (total + 255u) / 256u;
  hipLaunchKernelGGL(grid_encode_kernel, dim3(blocks), dim3(256), 0, stream,
                     in, emb, out, B);
}

// Round 2
// 1171.616 us; speedup vs baseline: 1.0547x; 1.0547x over previous
//
#include <hip/hip_runtime.h>
#include <cstdint>

// GridEncoder forward (torch-ngp semantics), MI355X.
// B = 1048576 points, D=3, L=16 levels, C=2, H=16, per_level_scale=2.0,
// log2_hashmap_size=19, align_corners=False.
//
// Level metadata (from the reference's _level_meta()):
//   res(l)   = 16 << l
//   scale(l) = res - 1            (exact in fp32)
//   dense levels: 0,1,2 (offsets 0, 4920, 40864), base = res+1,
//     idx = cx + cy*base + cz*base^2   (mod size is identity)
//   hashed levels: 3..15, size = 2^19 -> idx = hash & 0x7FFFF
//     offset(l) = l*524288 - 1257368
//   fast_hash primes: (1, 2654435761, 805459861)
//
// R2 layout change (vs R1's thread-per-(point,level)): one thread per POINT,
// rolled loop over levels (2 per iteration). Rationale: each hashed level's
// table is exactly 4 MiB = one XCD L2. With all waves advancing through the
// level loop in phase, the instantaneous gather working set is ~1-2 tables,
// so the per-XCD L2 can cache it (R1 mixed all 16 levels per wave -> 52 MB
// working set -> FETCH_SIZE 3.87 GB). Also: inputs read once (not 16x), and
// each thread owns its point's full 128 B output row -> line-covering float4
// stores.

namespace {

__device__ __forceinline__ void level_setup(
    float x, float y, float z, uint32_t l,
    uint32_t idx[8], float w[8]) {
  // l is wave-uniform (loop counter) -> all the l-dependent math is scalar.
  uint32_t res = 16u << l;
  float scale = (float)res - 1.0f;

  float px = x * scale + 0.5f;
  float py = y * scale + 0.5f;
  float pz = z * scale + 0.5f;
  float gx = floorf(px), gy = floorf(py), gz = floorf(pz);
  float rx = px - gx, ry = py - gy, rz = pz - gz;
  uint32_t ix = (uint32_t)gx, iy = (uint32_t)gy, iz = (uint32_t)gz;

  uint32_t off = (l >= 3u) ? (l * 524288u - 1257368u)
                           : ((l == 0u) ? 0u : ((l == 1u) ? 4920u : 40864u));
  bool hashed = (l >= 3u);

  uint32_t base = res + 1u;
  uint32_t bb = base * base;
  const uint32_t P2 = 2654435761u, P3 = 805459861u;

  uint32_t dy0 = iy * base, dy1 = dy0 + base;
  uint32_t dz0 = iz * bb,   dz1 = dz0 + bb;
  uint32_t hy0 = iy * P2,   hy1 = hy0 + P2;
  uint32_t hz0 = iz * P3,   hz1 = hz0 + P3;

#pragma unroll
  for (int c = 0; c < 8; ++c) {
    uint32_t cx = ix + (uint32_t)(c & 1);
    uint32_t h = (cx ^ ((c & 2) ? hy1 : hy0) ^ ((c & 4) ? hz1 : hz0)) & 0x7FFFFu;
    uint32_t d = cx + ((c & 2) ? dy1 : dy0) + ((c & 4) ? dz1 : dz0);
    idx[c] = (hashed ? h : d) + off;
  }

  float wx1 = rx, wx0 = 1.0f - rx;
  float wy1 = ry, wy0 = 1.0f - ry;
  float wz1 = rz, wz0 = 1.0f - rz;
#pragma unroll
  for (int c = 0; c < 8; ++c) {
    w[c] = ((c & 1) ? wx1 : wx0) *
           ((c & 2) ? wy1 : wy0) *
           ((c & 4) ? wz1 : wz0);
  }
}

__global__ __launch_bounds__(256) void grid_encode_kernel(
    const float* __restrict__ in,      // [B,3] in [-1,1]
    const float2* __restrict__ emb,    // [7131240] float2
    float4* __restrict__ out,          // [B*8] float4 (= [B,16] float2)
    uint32_t B) {
  uint32_t p = blockIdx.x * 256u + threadIdx.x;
  if (p >= B) return;

  float x = (in[p * 3 + 0] + 1.0f) * 0.5f;
  float y = (in[p * 3 + 1] + 1.0f) * 0.5f;
  float z = (in[p * 3 + 2] + 1.0f) * 0.5f;

  float4 acc[8];

  // Rolled over levels on purpose: keeps all in-flight waves on the same
  // 1-2 levels at any instant (L2 working-set control). 2 levels/iter for
  // 16 outstanding gathers per thread.
#pragma unroll 1
  for (uint32_t l = 0; l < 16u; l += 2u) {
    uint32_t ia[8], ib[8];
    float wa[8], wb[8];
    level_setup(x, y, z, l,      ia, wa);
    level_setup(x, y, z, l + 1u, ib, wb);

    float2 ea[8], eb[8];
#pragma unroll
    for (int c = 0; c < 8; ++c) ea[c] = emb[ia[c]];
#pragma unroll
    for (int c = 0; c < 8; ++c) eb[c] = emb[ib[c]];

    float a0 = 0.0f, a1 = 0.0f, b0 = 0.0f, b1 = 0.0f;
#pragma unroll
    for (int c = 0; c < 8; ++c) {
      a0 = fmaf(wa[c], ea[c].x, a0);
      a1 = fmaf(wa[c], ea[c].y, a1);
      b0 = fmaf(wb[c], eb[c].x, b0);
      b1 = fmaf(wb[c], eb[c].y, b1);
    }
    acc[l >> 1] = make_float4(a0, a1, b0, b1);
  }

  // 128 B contiguous per thread; every 64 B line fully written by this lane.
#pragma unroll
  for (int j = 0; j < 8; ++j) out[p * 8u + (uint32_t)j] = acc[j];
}

}  // namespace

extern "C" void kernel_launch(void* const* d_in, const int* in_sizes, int n_in,
                              void* d_out, int out_size, void* d_ws, size_t ws_size,
                              hipStream_t stream) {
  (void)n_in; (void)out_size; (void)d_ws; (void)ws_size;
  const float* in = (const float*)d_in[0];
  const float2* emb = (const float2*)d_in[1];
  float4* out = (float4*)d_out;
  uint32_t B = (uint32_t)(in_sizes[0] / 3);
  uint32_t blocks = (B + 255u) / 256u;
  hipLaunchKernelGGL(grid_encode_kernel, dim3(blocks), dim3(256), 0, stream,
                     in, emb, out, B);
}

// Round 3
// 617.931 us; speedup vs baseline: 1.9998x; 1.8960x over previous
//
#include <hip/hip_runtime.h>
#include <cstdint>

// GridEncoder forward (torch-ngp semantics), MI355X.
// B = 1048576 points, D=3, L=16 levels, C=2, H=16, per_level_scale=2.0,
// log2_hashmap_size=19, align_corners=False.
//
// Level metadata (from the reference's _level_meta()):
//   res(l)   = 16 << l
//   scale(l) = res - 1            (exact in fp32)
//   dense levels: 0,1,2 (offsets 0, 4920, 40864), base = res+1,
//     idx = cx + cy*base + cz*base^2   (mod size is identity)
//   hashed levels: 3..15, size = 2^19 -> idx = hash & 0x7FFFF
//     offset(l) = l*524288 - 1257368
//   fast_hash primes: (1, 2654435761, 805459861)
//
// R3 structure: LEVEL-PHASED DISPATCH. R2 showed every hashed gather misses
// L2 (FETCH 3.58 GB ~= 104M x 32 B sectors) because resident blocks sit at
// random level-loop phases -> 52 MB working set vs 4 MiB XCD L2. Fix: put
// the level in blockIdx.y. HW dispatches x-fastest, so the GPU sweeps
// levels as sequential 4096-block bands; in-flight blocks span <=2 bands ->
// instantaneous working set 1-2 tables (4-8 MiB), each table ~ one XCD L2.
// Output is produced level-major into d_ws (coalesced 8 B stores,
// nontemporal so the stream doesn't evict table lines), then a separate
// LDS-transpose kernel emits the [B,16,2] layout with lane-contiguous
// stores (also fixes R2's 134->354 MB write amplification from strided
// per-thread-row stores).

namespace {

using f32x2 = __attribute__((ext_vector_type(2))) float;
using f32x4 = __attribute__((ext_vector_type(4))) float;

__device__ __forceinline__ void level_setup(
    float x, float y, float z, uint32_t l,
    uint32_t idx[8], float w[8]) {
  uint32_t res = 16u << l;
  float scale = (float)res - 1.0f;

  float px = x * scale + 0.5f;
  float py = y * scale + 0.5f;
  float pz = z * scale + 0.5f;
  float gx = floorf(px), gy = floorf(py), gz = floorf(pz);
  float rx = px - gx, ry = py - gy, rz = pz - gz;
  uint32_t ix = (uint32_t)gx, iy = (uint32_t)gy, iz = (uint32_t)gz;

  uint32_t off = (l >= 3u) ? (l * 524288u - 1257368u)
                           : ((l == 0u) ? 0u : ((l == 1u) ? 4920u : 40864u));
  bool hashed = (l >= 3u);

  uint32_t base = res + 1u;
  uint32_t bb = base * base;
  const uint32_t P2 = 2654435761u, P3 = 805459861u;

  uint32_t dy0 = iy * base, dy1 = dy0 + base;
  uint32_t dz0 = iz * bb,   dz1 = dz0 + bb;
  uint32_t hy0 = iy * P2,   hy1 = hy0 + P2;
  uint32_t hz0 = iz * P3,   hz1 = hz0 + P3;

#pragma unroll
  for (int c = 0; c < 8; ++c) {
    uint32_t cx = ix + (uint32_t)(c & 1);
    uint32_t h = (cx ^ ((c & 2) ? hy1 : hy0) ^ ((c & 4) ? hz1 : hz0)) & 0x7FFFFu;
    uint32_t d = cx + ((c & 2) ? dy1 : dy0) + ((c & 4) ? dz1 : dz0);
    idx[c] = (hashed ? h : d) + off;
  }

  float wx1 = rx, wx0 = 1.0f - rx;
  float wy1 = ry, wy0 = 1.0f - ry;
  float wz1 = rz, wz0 = 1.0f - rz;
#pragma unroll
  for (int c = 0; c < 8; ++c) {
    w[c] = ((c & 1) ? wx1 : wx0) *
           ((c & 2) ? wy1 : wy0) *
           ((c & 4) ? wz1 : wz0);
  }
}

// ---- Pass 1: level-phased gather, writes level-major ws[l*B + p] ----
__global__ __launch_bounds__(256) void gather_lm_kernel(
    const float* __restrict__ in,      // [B,3] in [-1,1]
    const f32x2* __restrict__ emb,     // [7131240] float2
    f32x2* __restrict__ ws,            // [16*B] float2, level-major
    uint32_t B) {
  uint32_t l = blockIdx.y;                       // level: slowest dispatch dim
  uint32_t p = blockIdx.x * 256u + threadIdx.x;  // point
  if (p >= B) return;

  // streaming input: nontemporal so it doesn't evict table lines in L2
  float x = (__builtin_nontemporal_load(&in[p * 3 + 0]) + 1.0f) * 0.5f;
  float y = (__builtin_nontemporal_load(&in[p * 3 + 1]) + 1.0f) * 0.5f;
  float z = (__builtin_nontemporal_load(&in[p * 3 + 2]) + 1.0f) * 0.5f;

  uint32_t idx[8];
  float w[8];
  level_setup(x, y, z, l, idx, w);

  f32x2 e[8];
#pragma unroll
  for (int c = 0; c < 8; ++c) e[c] = emb[idx[c]];

  float o0 = 0.0f, o1 = 0.0f;
#pragma unroll
  for (int c = 0; c < 8; ++c) {
    o0 = fmaf(w[c], e[c].x, o0);
    o1 = fmaf(w[c], e[c].y, o1);
  }

  f32x2 r; r.x = o0; r.y = o1;
  __builtin_nontemporal_store(r, &ws[(size_t)l * B + p]);  // coalesced 8 B/lane
}

// ---- Pass 2: transpose level-major ws -> point-major out ----
// Block: 256 threads, 256 points. LDS layout [l][point] with pad 257 to
// keep the coalesced writes conflict-free; reads are two ds_read_b64 per
// float4 (bank pattern spreads over all 32 banks).
__global__ __launch_bounds__(256) void transpose_kernel(
    const f32x2* __restrict__ ws,   // [16*B] level-major
    f32x4* __restrict__ out,        // [B*8] float4 == [B,16,2] floats
    uint32_t B) {
  __shared__ f32x2 lds[16 * 257];
  uint32_t tid = threadIdx.x;
  uint32_t p0 = blockIdx.x * 256u;

#pragma unroll
  for (uint32_t l = 0; l < 16u; ++l) {
    lds[l * 257u + tid] =
        __builtin_nontemporal_load(&ws[(size_t)l * B + p0 + tid]);
  }
  __syncthreads();

#pragma unroll
  for (uint32_t m = 0; m < 8u; ++m) {
    uint32_t lin = m * 256u + tid;     // 0..2047 = point-in-block*8 + pair
    uint32_t q = lin >> 3;             // point in block
    uint32_t j2 = lin & 7u;            // which float4 of the 128 B row
    f32x2 a = lds[(2u * j2)      * 257u + q];
    f32x2 b = lds[(2u * j2 + 1u) * 257u + q];
    f32x4 v; v.x = a.x; v.y = a.y; v.z = b.x; v.w = b.y;
    // lane-contiguous: consecutive lanes write consecutive 16 B
    __builtin_nontemporal_store(v, &out[(size_t)p0 * 8u + lin]);
  }
}

// ---- Fallback (ws too small): R2 single-pass kernel ----
__global__ __launch_bounds__(256) void grid_encode_fallback(
    const float* __restrict__ in, const f32x2* __restrict__ emb,
    f32x4* __restrict__ out, uint32_t B) {
  uint32_t p = blockIdx.x * 256u + threadIdx.x;
  if (p >= B) return;
  float x = (in[p * 3 + 0] + 1.0f) * 0.5f;
  float y = (in[p * 3 + 1] + 1.0f) * 0.5f;
  float z = (in[p * 3 + 2] + 1.0f) * 0.5f;
#pragma unroll 1
  for (uint32_t l = 0; l < 16u; l += 2u) {
    uint32_t ia[8], ib[8]; float wa[8], wb[8];
    level_setup(x, y, z, l, ia, wa);
    level_setup(x, y, z, l + 1u, ib, wb);
    f32x2 ea[8], eb[8];
#pragma unroll
    for (int c = 0; c < 8; ++c) ea[c] = emb[ia[c]];
#pragma unroll
    for (int c = 0; c < 8; ++c) eb[c] = emb[ib[c]];
    float a0 = 0, a1 = 0, b0 = 0, b1 = 0;
#pragma unroll
    for (int c = 0; c < 8; ++c) {
      a0 = fmaf(wa[c], ea[c].x, a0);
      a1 = fmaf(wa[c], ea[c].y, a1);
      b0 = fmaf(wb[c], eb[c].x, b0);
      b1 = fmaf(wb[c], eb[c].y, b1);
    }
    f32x4 v; v.x = a0; v.y = a1; v.z = b0; v.w = b1;
    out[(size_t)p * 8u + (l >> 1)] = v;
  }
}

}  // namespace

extern "C" void kernel_launch(void* const* d_in, const int* in_sizes, int n_in,
                              void* d_out, int out_size, void* d_ws, size_t ws_size,
                              hipStream_t stream) {
  (void)n_in; (void)out_size;
  const float* in = (const float*)d_in[0];
  const f32x2* emb = (const f32x2*)d_in[1];
  f32x4* out = (f32x4*)d_out;
  uint32_t B = (uint32_t)(in_sizes[0] / 3);
  uint32_t pblocks = (B + 255u) / 256u;

  size_t ws_needed = (size_t)16 * B * sizeof(f32x2);   // 128 MiB at B=1M
  if (ws_size >= ws_needed) {
    f32x2* ws = (f32x2*)d_ws;
    hipLaunchKernelGGL(gather_lm_kernel, dim3(pblocks, 16), dim3(256), 0,
                       stream, in, emb, ws, B);
    hipLaunchKernelGGL(transpose_kernel, dim3(pblocks), dim3(256), 0,
                       stream, ws, out, B);
  } else {
    hipLaunchKernelGGL(grid_encode_fallback, dim3(pblocks), dim3(256), 0,
                       stream, in, emb, out, B);
  }
}